// Round 6
// baseline (126.674 us; speedup 1.0000x reference)
//
#include <hip/hip_runtime.h>

// ---------------------------------------------------------------------------
// ConvQuantizationWrapper: exact integer reformulation, MFMA i8, LDS-staged.
// out = [conv3x3(q_in, tc(q_w)) + zp*conv3x3(ones, q_w)] / (sa*sw) + bias
//   q_in = clip(round(x*sa - zp), 0, 255) (u8);  q_w = round(w*sw)
// qa holds (q_in - 128) i8 in zero-padded NHWC [n][58][58][64c].
// conv: block stages 6 qa rows into LDS, A frags via ds_read_b128.
// R6: LDS pixel stride 64 B -> 80 B (20 dwords). With stride 64 the lane
// start dwords were ln*16 mod 32 = {0,16} -> ~4-way bank conflict on every
// b128 read (~12 us of LDS-pipe serialization/CU). Stride 20 dwords gives
// ln*20 mod 32 = {0,20,8,28,16,4,24,12}: each 8-lane service group covers
// all 32 banks disjointly -> conflict-free.
// Border corrections via a 9-case x 64-och table (built in prep_wq) in LDS.
// ---------------------------------------------------------------------------

typedef int v4i __attribute__((ext_vector_type(4)));

#define QA_ROW   3712        // 58 cols * 64 B (global qa layout)
#define QA_IMG   215296      // 58 rows * QA_ROW
#define QA_BYTES 13778944    // 64 images
#define LPX      80          // LDS bytes per pixel (64 data + 16 pad)
#define CORR_OFF 27840       // 348 px * 80 B
#define LDS_SZ   30144       // + 9*64*4 corr table

// ---- fused weight prep: quantize + 9-case border-correction table ----
// corr_tab[case][o], case = vcase*3 + hcase; vcase: 0 interior, 1 top(h==0),
// 2 bottom(h==55); hcase: 0 interior, 1 left(w==0), 2 right(w==55).
__global__ __launch_bounds__(64) void prep_wq(const float* __restrict__ wt,
                                              const float* __restrict__ sw_p,
                                              const float* __restrict__ zp_p,
                                              signed char* __restrict__ w8,
                                              float* __restrict__ corr_tab) {
  const int o = blockIdx.x;             // 0..63
  const int i = threadIdx.x;            // input channel 0..63
  const float sw = sw_p[0];
  const float* wp = wt + (size_t)(o * 64 + i) * 9;
  int q[9];
#pragma unroll
  for (int k = 0; k < 9; ++k) q[k] = (int)rintf(wp[k] * sw);
#pragma unroll
  for (int k = 0; k < 9; ++k)
    w8[(o * 9 + k) * 64 + i] = (signed char)(q[k] & 255);

  int stc[9], srw[9];
#pragma unroll
  for (int k = 0; k < 9; ++k) {
    int a = (int)(signed char)(q[k] & 255);   // two's-complement i8 value
    int b = q[k];
#pragma unroll
    for (int off = 32; off; off >>= 1) {      // xor butterfly: sum in ALL lanes
      a += __shfl_xor(a, off);
      b += __shfl_xor(b, off);
    }
    stc[k] = a; srw[k] = b;
  }
  const float zp = zp_p[0];
  if (i < 9) {                          // lane i computes border case i
    const int v = i / 3, hc = i % 3;
    float corr = 0.0f;
#pragma unroll
    for (int k = 0; k < 9; ++k) {
      const int kh = k / 3, kw = k % 3;
      const bool drop = (v == 1 && kh == 0) || (v == 2 && kh == 2) ||
                        (hc == 1 && kw == 0) || (hc == 2 && kw == 2);
      if (!drop) corr += 128.0f * (float)stc[k] + zp * (float)srw[k];
    }
    corr_tab[i * 64 + o] = corr;
  }
}

// ---- quantize activations: NCHW fp32 -> padded NHWC i8 (q_in - 128) ----
// 2 rows per block; float4 coalesced loads, LDS byte-transpose (stride 68).
__global__ __launch_bounds__(256) void quant_a(const float* __restrict__ x,
                                               const float* __restrict__ sa_p,
                                               const float* __restrict__ zp_p,
                                               signed char* __restrict__ qa) {
  __shared__ int ldsbuf[1904];          // 2 * 56 * 68 bytes
  signed char* lds = (signed char*)ldsbuf;
  const int bx = blockIdx.x;            // 0..27 -> rows 2bx, 2bx+1
  const int n = blockIdx.y;
  const int t = threadIdx.x;
  const float sa = sa_p[0], zp = zp_p[0];
  const float* xim = x + (size_t)n * 200704;    // 64 * 3136
  const int h0 = bx * 2;

#pragma unroll
  for (int it = 0; it < 7; ++it) {
    const int idx = t + 256 * it;       // 0..1791: [r][c][w4]
    const int r = idx >= 896;
    const int rem = idx - 896 * r;
    const int c = (rem * 2341) >> 15;   // rem / 14  (exact for rem < 896)
    const int w4 = rem - c * 14;
    const float4 v = *(const float4*)(xim + (size_t)c * 3136 + (h0 + r) * 56 + w4 * 4);
    signed char* dst = lds + r * 3808 + w4 * 272 + c;   // [(4*w4+e)*68 + c]
    const float vv[4] = {v.x, v.y, v.z, v.w};
#pragma unroll
    for (int e = 0; e < 4; ++e) {
      float tq;
      {
#pragma clang fp contract(off)
        tq = vv[e] * sa - zp;           // match ref: mul then sub, no fma
      }
      float qf = rintf(tq);             // half-to-even, like jnp.round
      qf = fminf(fmaxf(qf, 0.0f), 255.0f);
      dst[e * 68] = (signed char)((int)qf - 128);
    }
  }
  __syncthreads();

  signed char* const qim = qa + (size_t)n * QA_IMG;
#pragma unroll
  for (int it = 0; it < 2; ++it) {
    const int idx = t + 256 * it;
    if (idx < 448) {                    // interior: 2 rows x 56 cols x 16B quads
      const int r = idx >= 224;
      const int u = idx - 224 * r;
      const int w = u >> 2, q2 = u & 3;
      const unsigned* s = (const unsigned*)(lds + r * 3808 + w * 68 + q2 * 16);
      const uint4 vv = make_uint4(s[0], s[1], s[2], s[3]);
      *((uint4*)(qim + (size_t)(h0 + r + 1) * QA_ROW + (w + 1) * 64 + q2 * 16)) = vv;
    } else if (idx < 464) {             // col pads: col 0 and col 57, both rows
      const int p = idx - 448;
      const int r = p >> 3;
      const int side = (p >> 2) & 1;
      const int j = p & 3;
      *((uint4*)(qim + (size_t)(h0 + r + 1) * QA_ROW + side * 57 * 64 + j * 16)) =
          make_uint4(0, 0, 0, 0);
    }
  }
  if (bx == 0 && t < 232)               // top pad row
    ((uint4*)qim)[t] = make_uint4(0, 0, 0, 0);
  if (bx == 27 && t < 232)              // bottom pad row
    ((uint4*)(qim + (size_t)57 * QA_ROW))[t] = make_uint4(0, 0, 0, 0);
}

// ---- main conv: LDS-staged implicit GEMM on v_mfma_i32_16x16x64_i8 ----
// grid (14, 64): block = one n, 4 output rows (224 px), all 64 och.
// 4 waves = (px-half 0/1) x (och-pair 0/1). Wave: 7 M-tiles of 16 px; per
// tile 9 ds_read_b128 A-frags, each feeding 2 MFMAs (och groups oa, oa+16).
__global__ __launch_bounds__(256, 4) void conv_mfma(
    const signed char* __restrict__ qa, const signed char* __restrict__ w8,
    const float* __restrict__ corr_tab, const float* __restrict__ bias,
    const float* __restrict__ sa_p, const float* __restrict__ sw_p,
    float* __restrict__ out) {
  __shared__ __align__(16) signed char lds[LDS_SZ];
  const int tid = threadIdx.x;
  const int n = blockIdx.y;
  const int h0 = blockIdx.x * 4;        // output rows h0..h0+3; qa rows h0..h0+5

  // stage qa rows (348 px -> stride-80 LDS) + corr table (144 uint4, linear)
  {
    const uint4* src = (const uint4*)(qa + (size_t)n * QA_IMG + (size_t)h0 * QA_ROW);
    const uint4* csrc = (const uint4*)corr_tab;
#pragma unroll
    for (int it = 0; it < 6; ++it) {    // 1536 = 6 * 256 exactly
      const int idx = tid + it * 256;
      if (idx < 1392) {
        const int px = idx >> 2, ch = idx & 3;
        *(uint4*)(lds + px * LPX + ch * 16) = src[idx];
      } else {
        *(uint4*)(lds + CORR_OFF + (idx - 1392) * 16) = csrc[idx - 1392];
      }
    }
  }
  __syncthreads();

  const int lane = tid & 63;
  const int wv = tid >> 6;
  const int phalf = wv & 1;             // px offset 112*phalf
  const int ogp = wv >> 1;              // och 32*ogp
  const int ln = lane & 15;
  const int kg = lane >> 4;             // k-group: bytes kg*16..kg*16+15
  const int oa = ogp * 32 + ln;         // first och; second is oa+16

  // B fragments for both och groups: B[n=ln][k = kg*16 + j] per tap
  const signed char* wba = w8 + (size_t)oa * 576 + kg * 16;
  v4i Ba[9], Bb[9];
#pragma unroll
  for (int t = 0; t < 9; ++t) {
    Ba[t] = *(const v4i*)(wba + t * 64);
    Bb[t] = *(const v4i*)(wba + 9216 + t * 64);   // (oa+16)*576
  }

  const float sa = sa_p[0], sw = sw_p[0];
  const float rden = 1.0f / (sw * sa);
  const float boa = bias[oa], bob = bias[oa + 16];
  const float* ctab = (const float*)(lds + CORR_OFF);
  const float cFa = ctab[oa];           // interior (case 0) corrections
  const float cFb = ctab[oa + 16];
  float* const outa = out + (size_t)(n * 64 + oa) * 3136 + h0 * 56;
  float* const outb = outa + 16 * 3136;

#pragma unroll 1
  for (int t = 0; t < 7; ++t) {
    const int pb = phalf * 112 + t * 16;          // block-relative px tile base
    const int pa = pb + ln;                       // this lane's A-row px (0..223)
    const int hr = (pa * 9363) >> 19;             // pa / 56 (exact)
    const int wc = pa - hr * 56;
    const signed char* ab = lds + (hr * 58 + wc) * LPX + kg * 16;
    v4i acca = {0, 0, 0, 0}, accb = {0, 0, 0, 0};
#pragma unroll
    for (int kh = 0; kh < 3; ++kh) {
#pragma unroll
      for (int kw = 0; kw < 3; ++kw) {
        const v4i A = *(const v4i*)(ab + (kh * 58 + kw) * LPX);
        acca = __builtin_amdgcn_mfma_i32_16x16x64_i8(A, Ba[kh * 3 + kw], acca, 0, 0, 0);
        accb = __builtin_amdgcn_mfma_i32_16x16x64_i8(A, Bb[kh * 3 + kw], accb, 0, 0, 0);
      }
    }
    // epilogue: C/D row(px) = kg*4 + reg, col(och) = ln
    const int pxb = pb + kg * 4;
    float ta[4], tb[4];
#pragma unroll
    for (int e = 0; e < 4; ++e) {
      const int p = pxb + e;
      const int hh = (p * 9363) >> 19;
      const int ww = p - hh * 56;
      const int hg = h0 + hh;
      float ca = cFa, cb = cFb;
      if ((hg == 0) | (hg == 55) | (ww == 0) | (ww == 55)) {   // rare border
        const int vcase = (hg == 0) ? 1 : ((hg == 55) ? 2 : 0);
        const int hcase = (ww == 0) ? 1 : ((ww == 55) ? 2 : 0);
        const int cidx = (vcase * 3 + hcase) * 64;
        ca = ctab[cidx + oa];
        cb = ctab[cidx + oa + 16];
      }
      ta[e] = ((float)acca[e] + ca) * rden + boa;
      tb[e] = ((float)accb[e] + cb) * rden + bob;
    }
    *(float4*)(outa + pxb) = make_float4(ta[0], ta[1], ta[2], ta[3]);
    *(float4*)(outb + pxb) = make_float4(tb[0], tb[1], tb[2], tb[3]);
  }
}

extern "C" void kernel_launch(void* const* d_in, const int* in_sizes, int n_in,
                              void* d_out, int out_size, void* d_ws, size_t ws_size,
                              hipStream_t stream) {
  const float* x    = (const float*)d_in[0];
  const float* wt   = (const float*)d_in[1];
  const float* bias = (const float*)d_in[2];
  const float* sa   = (const float*)d_in[3];
  const float* sw   = (const float*)d_in[4];
  const float* zp   = (const float*)d_in[5];
  float* out = (float*)d_out;

  char* ws = (char*)d_ws;
  signed char* qa = (signed char*)ws;                       // QA_BYTES
  signed char* w8 = (signed char*)(ws + QA_BYTES);          // 36,864 B
  float* corr_tab = (float*)(ws + QA_BYTES + 36864);        // 2,304 B

  prep_wq<<<64, 64, 0, stream>>>(wt, sw, zp, w8, corr_tab);
  quant_a<<<dim3(28, 64), 256, 0, stream>>>(x, sa, zp, qa);
  conv_mfma<<<dim3(14, 64), 256, 0, stream>>>(qa, w8, corr_tab, bias, sa, sw, out);
}